// Round 4
// baseline (167.366 us; speedup 1.0000x reference)
//
#include <hip/hip_runtime.h>

#define H_ 200
#define W_ 200
#define DELX_ 1.5f
#define DELY_ 1.5f
#define NXV_ 256
#define NYV_ 256
#define NZV_ 256
#define EPS_ 1e-8f
#define NSEG 16           // x-slabs of 16 planes (round-0 partition, proven absmax 3.0)
#define SEGS_PER_BLK 8    // block = 64 px * 8 segs = 512 threads; 2 blocks/tile
#define TILE_R 4          // 4x16 detector patch = 64 px = one wave per seg
#define TILE_C 16
#define TROWS (H_ / TILE_R)              // 50
#define TCOLS ((W_ + TILE_C - 1) / TILE_C)  // 13 (padded: last col tile partial)
#define TILES_PER_IMG (TROWS * TCOLS)    // 650
#define G_ 8              // steps per group (gathers in flight per group)
#define MAXG 10           // capacity identical to round-0: <=10 groups marched

// alpha for integer plane k — SAME source expression as round-0 so the
// compiler's contraction is bitwise-identical (proven absmax 3.0).
__device__ __forceinline__ float alpha_mul(float k, float sp, float src, float inv_sdd) {
    return (k * sp - src) * inv_sdd;
}

// March one group of G_ steps; gather issued AT step u (same address round-0
// stored into off[u]) so it ages under the remaining march. Numerics bitwise
// round-0: unclamped a_cur, ok-select step, exit-face update suppression.
#define MARCH_ISSUE(VC, SC)                                                   \
    _Pragma("unroll")                                                         \
    for (int u = 0; u < G_; ++u) {                                            \
        float an = fminf(axv, fminf(ayv, azv));                               \
        bool ok = (an <= aend);                                               \
        SC[u] = ok ? (an - a_cur) : 0.0f;                                     \
        VC[u] = vol[off_cur];               /* issue gather for this step */  \
        a_cur = an;                                                           \
        bool upd = (an < aend);                                               \
        bool cx = (axv == an), cy = (ayv == an), cz = (azv == an);            \
        kx = cx ? kx + dkx : kx;                                              \
        ky = cy ? ky + dky : ky;                                              \
        kz = cz ? kz + dkz : kz;                                              \
        off_cur += ((cx && upd) ? doffx : 0)                                  \
                 + ((cy && upd) ? doffy : 0)                                  \
                 + ((cz && upd) ? doffz : 0);                                 \
        axv = alpha_mul(kx, spx, sx, inv_dx);  /* bitwise-stable recompute */ \
        ayv = alpha_mul(ky, spy, sy, inv_dy);                                 \
        azv = alpha_mul(kz, spz, sz, inv_dz);                                 \
    }

// Same march, but also drain the PREVIOUS group's contributions (in order,
// one fma per step) — its gathers aged a full group of march work.
#define MARCH_ISSUE_CONSUME(VC, SC, VP, SP)                                   \
    _Pragma("unroll")                                                         \
    for (int u = 0; u < G_; ++u) {                                            \
        acc += VP[u] * SP[u];               /* consume prev group, in order */\
        float an = fminf(axv, fminf(ayv, azv));                               \
        bool ok = (an <= aend);                                               \
        SC[u] = ok ? (an - a_cur) : 0.0f;                                     \
        VC[u] = vol[off_cur];                                                 \
        a_cur = an;                                                           \
        bool upd = (an < aend);                                               \
        bool cx = (axv == an), cy = (ayv == an), cz = (azv == an);            \
        kx = cx ? kx + dkx : kx;                                              \
        ky = cy ? ky + dky : ky;                                              \
        kz = cz ? kz + dkz : kz;                                              \
        off_cur += ((cx && upd) ? doffx : 0)                                  \
                 + ((cy && upd) ? doffy : 0)                                  \
                 + ((cz && upd) ? doffz : 0);                                 \
        axv = alpha_mul(kx, spx, sx, inv_dx);                                 \
        ayv = alpha_mul(ky, spy, sy, inv_dy);                                 \
        azv = alpha_mul(kz, spz, sz, inv_dz);                                 \
    }

#define CONSUME(VP, SP)                                                       \
    _Pragma("unroll")                                                         \
    for (int u = 0; u < G_; ++u) { acc += VP[u] * SP[u]; }

__global__ void __launch_bounds__(512, 6)   // cap ~80-85 VGPR: fits 4 arrays + state, no spill
drr_partial(const float* __restrict__ vol,
            const float* __restrict__ spacing,
            const float* __restrict__ sdr,
            const float* __restrict__ rot,
            const float* __restrict__ trans,
            float* __restrict__ partials,
            int npix) {
    // --- bijective XCD swizzle (m204): same-XCD blocks cover contiguous tiles
    // within one seg-half -> better L2 locality on re-touched volume lines.
    const int nwg = gridDim.x;               // B * TILES_PER_IMG * 2
    const int q8 = nwg >> 3, r8 = nwg & 7;
    const int xcd = blockIdx.x & 7;
    const int sub = blockIdx.x >> 3;
    const int wg = (xcd < r8 ? xcd * (q8 + 1) : r8 * (q8 + 1) + (xcd - r8) * q8) + sub;

    const int ntiles = nwg >> 1;             // B * TILES_PER_IMG
    const int half    = (wg < ntiles) ? 0 : 1;
    const int tileBlk = wg - half * ntiles;

    const int t = threadIdx.x;
    const int pixLocal = t & 63;            // 0..63 : 4x16 patch per wave
    const int seg = (t >> 6) + (half << 3); // 0..15 ; wave = 64 px x 1 slab

    const int b    = tileBlk / TILES_PER_IMG;
    const int rem  = tileBlk % TILES_PER_IMG;
    const int ty   = rem / TCOLS;
    const int tx   = rem % TCOLS;
    const int i = ty * TILE_R + (pixLocal >> 4);   // 4 rows
    const int j = tx * TILE_C + (pixLocal & 15);   // 16 cols (may exceed W_-1: padded)

    // --- rotation matrix R = Rz(theta) Ry(phi) Rx(gamma) ---
    const float theta = rot[b * 3 + 0], phi = rot[b * 3 + 1], gamma = rot[b * 3 + 2];
    const float ct = cosf(theta), st = sinf(theta);
    const float cp = cosf(phi),   sp = sinf(phi);
    const float cg = cosf(gamma), sg = sinf(gamma);
    const float r00 = ct * cp,                r10 = st * cp,                r20 = -sp;
    const float r01 = ct * sp * sg - st * cg, r11 = st * sp * sg + ct * cg, r21 = cp * sg;
    const float r02 = ct * sp * cg + st * sg, r12 = st * sp * cg - ct * sg, r22 = cp * cg;

    const float sd = sdr[b];
    const float tx_ = trans[b * 3 + 0], ty_ = trans[b * 3 + 1], tz_ = trans[b * 3 + 2];
    const float sx = sd * r00 + tx_, sy = sd * r10 + ty_, sz = sd * r20 + tz_;
    const float cxx = -sd * r00 + tx_, cyy = -sd * r10 + ty_, czz = -sd * r20 + tz_;

    const float tco = ((float)(i - H_ / 2) + 1.0f) * DELX_;
    const float sco = ((float)(j - W_ / 2) + 1.0f) * DELY_;
    const float gx = r01 * tco + r02 * sco + cxx;
    const float gy = r11 * tco + r12 * sco + cyy;
    const float gz = r21 * tco + r22 * sco + czz;

    const float dx = gx - sx + EPS_;
    const float dy = gy - sy + EPS_;
    const float dz = gz - sz + EPS_;

    const float spx = spacing[0], spy = spacing[1], spz = spacing[2];
    const float inv_spx = 1.0f / spx, inv_spy = 1.0f / spy, inv_spz = 1.0f / spz;
    const float inv_dx = 1.0f / dx, inv_dy = 1.0f / dy, inv_dz = 1.0f / dz;

    const float a0x = alpha_mul(0.f, spx, sx, inv_dx), a1x = alpha_mul((float)NXV_, spx, sx, inv_dx);
    const float a0y = alpha_mul(0.f, spy, sy, inv_dy), a1y = alpha_mul((float)NYV_, spy, sy, inv_dy);
    const float a0z = alpha_mul(0.f, spz, sz, inv_dz), a1z = alpha_mul((float)NZV_, spz, sz, inv_dz);

    const float amin = fmaxf(fmaxf(fminf(a0x, a1x), fminf(a0y, a1y)), fminf(a0z, a1z));
    const float amax = fminf(fminf(fmaxf(a0x, a1x), fmaxf(a0y, a1y)), fmaxf(a0z, a1z));

    const float norm = sqrtf(dx * dx + dy * dy + dz * dz);

    // segment bounds at x-plane crossings (exact members of the crossing set)
    const float klo = (float)(seg * (NXV_ / NSEG));
    const float khi = (float)((seg + 1) * (NXV_ / NSEG));
    const float aA = alpha_mul(klo, spx, sx, inv_dx);
    const float aB = alpha_mul(khi, spx, sx, inv_dx);
    const float start = fmaxf(amin, fminf(aA, aB));
    const float aend  = fminf(amax, fmaxf(aA, aB));

    float acc = 0.0f;
    if (start < aend) {
        float kx, ky, kz, axv, ayv, azv, dkx, dky, dkz;
        {
            float kf = (start * dx + sx) * inv_spx;
            if (dx > 0.f) { dkx = 1.f;  kx = floorf(kf) + 1.f; }
            else          { dkx = -1.f; kx = ceilf(kf) - 1.f; }
            axv = alpha_mul(kx, spx, sx, inv_dx);
        }
        {
            float kf = (start * dy + sy) * inv_spy;
            if (dy > 0.f) { dky = 1.f;  ky = floorf(kf) + 1.f; }
            else          { dky = -1.f; ky = ceilf(kf) - 1.f; }
            ayv = alpha_mul(ky, spy, sy, inv_dy);
        }
        {
            float kf = (start * dz + sz) * inv_spz;
            if (dz > 0.f) { dkz = 1.f;  kz = floorf(kf) + 1.f; }
            else          { dkz = -1.f; kz = ceilf(kf) - 1.f; }
            azv = alpha_mul(kz, spz, sz, inv_dz);
        }

        // initial cell from first-interval midpoint (clamped once), then
        // incremental single-offset walk (exit-face crossing suppressed)
        int off_cur;
        {
            float an0 = fminf(axv, fminf(ayv, azv));
            float midv = 0.5f * (start + an0);
            int ix = (int)((sx + midv * dx) * inv_spx);   // trunc, matches ref
            int iy = (int)((sy + midv * dy) * inv_spy);
            int iz = (int)((sz + midv * dz) * inv_spz);
            ix = min(max(ix, 0), NXV_ - 1);
            iy = min(max(iy, 0), NYV_ - 1);
            iz = min(max(iz, 0), NZV_ - 1);
            off_cur = ((NXV_ - 1 - ix) * NYV_ + iy) * NZV_ + iz;  // flip axis 0
        }
        const int doffx = (dkx > 0.f) ? -(NYV_ * NZV_) : (NYV_ * NZV_);  // flipped x
        const int doffy = (dky > 0.f) ? NZV_ : -NZV_;
        const int doffz = (dkz > 0.f) ? 1 : -1;

        float a_cur = start;
        float vA[G_], sA[G_], vB[G_], sB[G_];

        // rotating 2-group pipeline: consume group g while marching g+1.
        // acc-add order and all marched values bitwise-identical to round-0;
        // early-finished lanes contribute exact +0.0 (stp=0, off frozen).
        MARCH_ISSUE(vA, sA);
        int g = 1;
        #pragma unroll 1
        while (true) {
            if (__all(a_cur > aend) || g >= MAXG) { CONSUME(vA, sA); break; }
            MARCH_ISSUE_CONSUME(vB, sB, vA, sA); ++g;
            if (__all(a_cur > aend) || g >= MAXG) { CONSUME(vB, sB); break; }
            MARCH_ISSUE_CONSUME(vA, sA, vB, sB); ++g;
        }
    }
    float result = acc * norm;

    // block-level reduce over the 8 segs of this half, fixed k-order summation
    __shared__ float red[SEGS_PER_BLK * 64];
    red[t] = result;
    __syncthreads();
    if (t < 64) {
        const int ii = ty * TILE_R + (t >> 4);
        const int jj = tx * TILE_C + (t & 15);
        if (jj < W_) {                          // mask padded columns
            const int opix = b * (H_ * W_) + ii * W_ + jj;
            float s = 0.0f;
            #pragma unroll
            for (int k = 0; k < SEGS_PER_BLK; k++) s += red[t + k * 64];
            partials[(size_t)half * npix + opix] = s;
        }
    }
}

__global__ void __launch_bounds__(256)
drr_combine(const float* __restrict__ partials, float* __restrict__ out, int npix) {
    int pix = blockIdx.x * blockDim.x + threadIdx.x;
    if (pix >= npix) return;
    out[pix] = partials[pix] + partials[(size_t)npix + pix];  // segs 0-7 then 8-15
}

extern "C" void kernel_launch(void* const* d_in, const int* in_sizes, int n_in,
                              void* d_out, int out_size, void* d_ws, size_t ws_size,
                              hipStream_t stream) {
    const float* vol     = (const float*)d_in[0];
    const float* spacing = (const float*)d_in[1];
    const float* sdr     = (const float*)d_in[2];
    const float* rot     = (const float*)d_in[3];
    const float* trans   = (const float*)d_in[4];
    float* out = (float*)d_out;

    const int B = in_sizes[2];
    const int npix = B * H_ * W_;
    float* partials = (float*)d_ws;     // 2 * npix floats

    const int nblocks = B * TILES_PER_IMG * 2;
    drr_partial<<<nblocks, 64 * SEGS_PER_BLK, 0, stream>>>(vol, spacing, sdr, rot, trans, partials, npix);
    drr_combine<<<(npix + 255) / 256, 256, 0, stream>>>(partials, out, npix);
}

// Round 5
// 129.609 us; speedup vs baseline: 1.2913x; 1.2913x over previous
//
#include <hip/hip_runtime.h>

#define H_ 200
#define W_ 200
#define DELX_ 1.5f
#define DELY_ 1.5f
#define NXV_ 256
#define NYV_ 256
#define NZV_ 256
#define EPS_ 1e-8f
#define NSEG 16           // x-slabs of 16 planes (round-0 partition, proven absmax 3.0)
#define SEGS_PER_BLK 8    // block = 64 px * 8 segs = 512 threads; 2 blocks/tile
#define TILE_R 4          // 4x16 detector patch = 64 px = one wave per seg
#define TILE_C 16
#define TROWS (H_ / TILE_R)              // 50
#define TCOLS ((W_ + TILE_C - 1) / TILE_C)  // 13 (padded: last col tile partial)
#define TILES_PER_IMG (TROWS * TCOLS)    // 650
#define MAXG 10           // capacity identical to round-0: <=10 groups of 8 steps

// alpha for integer plane k — SAME source expression as round-0 so the
// compiler's contraction is bitwise-identical (proven absmax 3.0).
__device__ __forceinline__ float alpha_mul(float k, float sp, float src, float inv_sdd) {
    return (k * sp - src) * inv_sdd;
}

// One marching step: gather issued into NAMED scalar V (same address round-0
// stored into off[u]); step into named scalar S. No arrays anywhere -> plain
// SSA values, immune to the scratch-demotion that killed rounds 2 and 4.
// Numerics bitwise round-0: unclamped a_cur, ok-select, exit-face suppression.
#define STEP1(V, S)                                                           \
    {                                                                         \
        float an = fminf(axv, fminf(ayv, azv));                               \
        bool ok = (an <= aend);                                               \
        S = ok ? (an - a_cur) : 0.0f;                                         \
        V = vol[off_cur];               /* gather ages under remaining march */\
        a_cur = an;                                                           \
        bool upd = (an < aend);                                               \
        bool cx = (axv == an), cy = (ayv == an), cz = (azv == an);            \
        kx = cx ? kx + dkx : kx;                                              \
        ky = cy ? ky + dky : ky;                                              \
        kz = cz ? kz + dkz : kz;                                              \
        off_cur += ((cx && upd) ? doffx : 0)                                  \
                 + ((cy && upd) ? doffy : 0)                                  \
                 + ((cz && upd) ? doffz : 0);                                 \
        axv = alpha_mul(kx, spx, sx, inv_dx);  /* bitwise-stable recompute */ \
        ayv = alpha_mul(ky, spy, sy, inv_dy);                                 \
        azv = alpha_mul(kz, spz, sz, inv_dz);                                 \
    }

#define MARCH8(P)                                                             \
    STEP1(P##v0, P##s0) STEP1(P##v1, P##s1) STEP1(P##v2, P##s2)               \
    STEP1(P##v3, P##s3) STEP1(P##v4, P##s4) STEP1(P##v5, P##s5)               \
    STEP1(P##v6, P##s6) STEP1(P##v7, P##s7)

// March group P while draining group Q (in order, one fma per step) — Q's
// gathers aged a full group (~300+ cyc) of independent march VALU work.
#define MARCH8_CONSUME(P, Q)                                                  \
    acc += Q##v0 * Q##s0; STEP1(P##v0, P##s0)                                 \
    acc += Q##v1 * Q##s1; STEP1(P##v1, P##s1)                                 \
    acc += Q##v2 * Q##s2; STEP1(P##v2, P##s2)                                 \
    acc += Q##v3 * Q##s3; STEP1(P##v3, P##s3)                                 \
    acc += Q##v4 * Q##s4; STEP1(P##v4, P##s4)                                 \
    acc += Q##v5 * Q##s5; STEP1(P##v5, P##s5)                                 \
    acc += Q##v6 * Q##s6; STEP1(P##v6, P##s6)                                 \
    acc += Q##v7 * Q##s7; STEP1(P##v7, P##s7)

#define CONSUME8(Q)                                                           \
    acc += Q##v0 * Q##s0; acc += Q##v1 * Q##s1;                               \
    acc += Q##v2 * Q##s2; acc += Q##v3 * Q##s3;                               \
    acc += Q##v4 * Q##s4; acc += Q##v5 * Q##s5;                               \
    acc += Q##v6 * Q##s6; acc += Q##v7 * Q##s7;

__global__ void __launch_bounds__(512, 6)   // cap ~85 VGPR; named-scalar pipeline ~70, no spill
drr_partial(const float* __restrict__ vol,
            const float* __restrict__ spacing,
            const float* __restrict__ sdr,
            const float* __restrict__ rot,
            const float* __restrict__ trans,
            float* __restrict__ partials,
            int npix) {
    // --- bijective XCD swizzle (m204): same-XCD blocks cover contiguous tiles
    // within one seg-half -> better L2 locality on re-touched volume lines.
    const int nwg = gridDim.x;               // B * TILES_PER_IMG * 2
    const int q8 = nwg >> 3, r8 = nwg & 7;
    const int xcd = blockIdx.x & 7;
    const int sub = blockIdx.x >> 3;
    const int wg = (xcd < r8 ? xcd * (q8 + 1) : r8 * (q8 + 1) + (xcd - r8) * q8) + sub;

    const int ntiles = nwg >> 1;             // B * TILES_PER_IMG
    const int half    = (wg < ntiles) ? 0 : 1;
    const int tileBlk = wg - half * ntiles;

    const int t = threadIdx.x;
    const int pixLocal = t & 63;            // 0..63 : 4x16 patch per wave
    const int seg = (t >> 6) + (half << 3); // 0..15 ; wave = 64 px x 1 slab

    const int b    = tileBlk / TILES_PER_IMG;
    const int rem  = tileBlk % TILES_PER_IMG;
    const int ty   = rem / TCOLS;
    const int tx   = rem % TCOLS;
    const int i = ty * TILE_R + (pixLocal >> 4);   // 4 rows
    const int j = tx * TILE_C + (pixLocal & 15);   // 16 cols (may exceed W_-1: padded)

    // --- rotation matrix R = Rz(theta) Ry(phi) Rx(gamma) ---
    const float theta = rot[b * 3 + 0], phi = rot[b * 3 + 1], gamma = rot[b * 3 + 2];
    const float ct = cosf(theta), st = sinf(theta);
    const float cp = cosf(phi),   sp = sinf(phi);
    const float cg = cosf(gamma), sg = sinf(gamma);
    const float r00 = ct * cp,                r10 = st * cp,                r20 = -sp;
    const float r01 = ct * sp * sg - st * cg, r11 = st * sp * sg + ct * cg, r21 = cp * sg;
    const float r02 = ct * sp * cg + st * sg, r12 = st * sp * cg - ct * sg, r22 = cp * cg;

    const float sd = sdr[b];
    const float tx_ = trans[b * 3 + 0], ty_ = trans[b * 3 + 1], tz_ = trans[b * 3 + 2];
    const float sx = sd * r00 + tx_, sy = sd * r10 + ty_, sz = sd * r20 + tz_;
    const float cxx = -sd * r00 + tx_, cyy = -sd * r10 + ty_, czz = -sd * r20 + tz_;

    const float tco = ((float)(i - H_ / 2) + 1.0f) * DELX_;
    const float sco = ((float)(j - W_ / 2) + 1.0f) * DELY_;
    const float gx = r01 * tco + r02 * sco + cxx;
    const float gy = r11 * tco + r12 * sco + cyy;
    const float gz = r21 * tco + r22 * sco + czz;

    const float dx = gx - sx + EPS_;
    const float dy = gy - sy + EPS_;
    const float dz = gz - sz + EPS_;

    const float spx = spacing[0], spy = spacing[1], spz = spacing[2];
    const float inv_spx = 1.0f / spx, inv_spy = 1.0f / spy, inv_spz = 1.0f / spz;
    const float inv_dx = 1.0f / dx, inv_dy = 1.0f / dy, inv_dz = 1.0f / dz;

    const float a0x = alpha_mul(0.f, spx, sx, inv_dx), a1x = alpha_mul((float)NXV_, spx, sx, inv_dx);
    const float a0y = alpha_mul(0.f, spy, sy, inv_dy), a1y = alpha_mul((float)NYV_, spy, sy, inv_dy);
    const float a0z = alpha_mul(0.f, spz, sz, inv_dz), a1z = alpha_mul((float)NZV_, spz, sz, inv_dz);

    const float amin = fmaxf(fmaxf(fminf(a0x, a1x), fminf(a0y, a1y)), fminf(a0z, a1z));
    const float amax = fminf(fminf(fmaxf(a0x, a1x), fmaxf(a0y, a1y)), fmaxf(a0z, a1z));

    const float norm = sqrtf(dx * dx + dy * dy + dz * dz);

    // segment bounds at x-plane crossings (exact members of the crossing set)
    const float klo = (float)(seg * (NXV_ / NSEG));
    const float khi = (float)((seg + 1) * (NXV_ / NSEG));
    const float aA = alpha_mul(klo, spx, sx, inv_dx);
    const float aB = alpha_mul(khi, spx, sx, inv_dx);
    const float start = fmaxf(amin, fminf(aA, aB));
    const float aend  = fminf(amax, fmaxf(aA, aB));

    float acc = 0.0f;
    if (start < aend) {
        float kx, ky, kz, axv, ayv, azv, dkx, dky, dkz;
        {
            float kf = (start * dx + sx) * inv_spx;
            if (dx > 0.f) { dkx = 1.f;  kx = floorf(kf) + 1.f; }
            else          { dkx = -1.f; kx = ceilf(kf) - 1.f; }
            axv = alpha_mul(kx, spx, sx, inv_dx);
        }
        {
            float kf = (start * dy + sy) * inv_spy;
            if (dy > 0.f) { dky = 1.f;  ky = floorf(kf) + 1.f; }
            else          { dky = -1.f; ky = ceilf(kf) - 1.f; }
            ayv = alpha_mul(ky, spy, sy, inv_dy);
        }
        {
            float kf = (start * dz + sz) * inv_spz;
            if (dz > 0.f) { dkz = 1.f;  kz = floorf(kf) + 1.f; }
            else          { dkz = -1.f; kz = ceilf(kf) - 1.f; }
            azv = alpha_mul(kz, spz, sz, inv_dz);
        }

        // initial cell from first-interval midpoint (clamped once), then
        // incremental single-offset walk (exit-face crossing suppressed)
        int off_cur;
        {
            float an0 = fminf(axv, fminf(ayv, azv));
            float midv = 0.5f * (start + an0);
            int ix = (int)((sx + midv * dx) * inv_spx);   // trunc, matches ref
            int iy = (int)((sy + midv * dy) * inv_spy);
            int iz = (int)((sz + midv * dz) * inv_spz);
            ix = min(max(ix, 0), NXV_ - 1);
            iy = min(max(iy, 0), NYV_ - 1);
            iz = min(max(iz, 0), NZV_ - 1);
            off_cur = ((NXV_ - 1 - ix) * NYV_ + iy) * NZV_ + iz;  // flip axis 0
        }
        const int doffx = (dkx > 0.f) ? -(NYV_ * NZV_) : (NYV_ * NZV_);  // flipped x
        const int doffy = (dky > 0.f) ? NZV_ : -NZV_;
        const int doffz = (dkz > 0.f) ? 1 : -1;

        float a_cur = start;
        float Av0, Av1, Av2, Av3, Av4, Av5, Av6, Av7;
        float As0, As1, As2, As3, As4, As5, As6, As7;
        float Bv0, Bv1, Bv2, Bv3, Bv4, Bv5, Bv6, Bv7;
        float Bs0, Bs1, Bs2, Bs3, Bs4, Bs5, Bs6, Bs7;

        // rotating 2-group pipeline over named scalars: consume group g while
        // marching g+1. acc-add order bitwise round-0; early-finished lanes
        // contribute exact +0.0 (stp=0, off frozen in-bounds).
        MARCH8(A);
        int g = 1;
        #pragma unroll 1
        while (true) {
            if (__all(a_cur > aend) || g >= MAXG) { CONSUME8(A); break; }
            MARCH8_CONSUME(B, A); ++g;
            if (__all(a_cur > aend) || g >= MAXG) { CONSUME8(B); break; }
            MARCH8_CONSUME(A, B); ++g;
        }
    }
    float result = acc * norm;

    // block-level reduce over the 8 segs of this half, fixed k-order summation
    __shared__ float red[SEGS_PER_BLK * 64];
    red[t] = result;
    __syncthreads();
    if (t < 64) {
        const int ii = ty * TILE_R + (t >> 4);
        const int jj = tx * TILE_C + (t & 15);
        if (jj < W_) {                          // mask padded columns
            const int opix = b * (H_ * W_) + ii * W_ + jj;
            float s = 0.0f;
            #pragma unroll
            for (int k = 0; k < SEGS_PER_BLK; k++) s += red[t + k * 64];
            partials[(size_t)half * npix + opix] = s;
        }
    }
}

__global__ void __launch_bounds__(256)
drr_combine(const float* __restrict__ partials, float* __restrict__ out, int npix) {
    int pix = blockIdx.x * blockDim.x + threadIdx.x;
    if (pix >= npix) return;
    out[pix] = partials[pix] + partials[(size_t)npix + pix];  // segs 0-7 then 8-15
}

extern "C" void kernel_launch(void* const* d_in, const int* in_sizes, int n_in,
                              void* d_out, int out_size, void* d_ws, size_t ws_size,
                              hipStream_t stream) {
    const float* vol     = (const float*)d_in[0];
    const float* spacing = (const float*)d_in[1];
    const float* sdr     = (const float*)d_in[2];
    const float* rot     = (const float*)d_in[3];
    const float* trans   = (const float*)d_in[4];
    float* out = (float*)d_out;

    const int B = in_sizes[2];
    const int npix = B * H_ * W_;
    float* partials = (float*)d_ws;     // 2 * npix floats

    const int nblocks = B * TILES_PER_IMG * 2;
    drr_partial<<<nblocks, 64 * SEGS_PER_BLK, 0, stream>>>(vol, spacing, sdr, rot, trans, partials, npix);
    drr_combine<<<(npix + 255) / 256, 256, 0, stream>>>(partials, out, npix);
}

// Round 6
// 122.384 us; speedup vs baseline: 1.3676x; 1.0590x over previous
//
#include <hip/hip_runtime.h>

#define H_ 200
#define W_ 200
#define DELX_ 1.5f
#define DELY_ 1.5f
#define NXV_ 256
#define NYV_ 256
#define NZV_ 256
#define EPS_ 1e-8f
#define NSEG 16           // x-slabs of 16 planes (round-0 partition, proven absmax 3.0)
#define TILE_R 4          // 4x16 detector patch = 64 px = one wave
#define TILE_C 16
#define TROWS (H_ / TILE_R)              // 50
#define TCOLS ((W_ + TILE_C - 1) / TILE_C)  // 13 (padded: last col tile partial)
#define TILES_PER_IMG (TROWS * TCOLS)    // 650 blocks/img -> single dispatch round
#define G4 4              // steps per group PER CHAIN (8 loads/group total, = round-0 MLP)
#define MAXG 20           // 20 groups * 4 = 80 steps/chain capacity (= round-0)

// alpha for integer plane k — SAME source expression as round-0 so the
// compiler's contraction is bitwise-identical (proven absmax 3.0 x4 rounds).
__device__ __forceinline__ float alpha_mul(float k, float sp, float src, float inv_sdd) {
    return (k * sp - src) * inv_sdd;
}

// One marching step for chain N — bitwise round-0 recurrence: unclamped a_cur,
// ok-select step, exit-face update suppression. All arrays die within the
// group iteration (round-0's proven no-spill pattern; NOTHING new lives
// across the loop backedge except the scalar chain state, same as round-0).
#define STEPC(N, u)                                                           \
    {                                                                         \
        float an = fminf(axv##N, fminf(ayv##N, azv##N));                      \
        bool ok = (an <= aend##N);                                            \
        stp##N[u] = ok ? (an - a_cur##N) : 0.0f;                              \
        off##N[u] = off_cur##N;                                               \
        a_cur##N = an;                                                        \
        bool upd = (an < aend##N);                                            \
        bool cx = (axv##N == an), cy = (ayv##N == an), cz = (azv##N == an);   \
        kx##N = cx ? kx##N + dkx : kx##N;                                     \
        ky##N = cy ? ky##N + dky : ky##N;                                     \
        kz##N = cz ? kz##N + dkz : kz##N;                                     \
        off_cur##N += ((cx && upd) ? doffx : 0)                               \
                    + ((cy && upd) ? doffy : 0)                               \
                    + ((cz && upd) ? doffz : 0);                              \
        axv##N = alpha_mul(kx##N, spx, sx, inv_dx);                           \
        ayv##N = alpha_mul(ky##N, spy, sy, inv_dy);                           \
        azv##N = alpha_mul(kz##N, spz, sz, inv_dz);                           \
    }

// Per-chain init: seg bounds + plane walk state + initial cell, bitwise
// round-0. Empty segs (start>=aend) get aend=-3e38: every step then yields
// stp=0 exactly, upd=false (offset frozen, in-bounds), done immediately —
// numerically identical to round-0's exec-masked idle lanes.
#define INIT_CH(N, SEGV)                                                      \
    float start##N, aend##N, kx##N, ky##N, kz##N, axv##N, ayv##N, azv##N;     \
    float a_cur##N, acc##N = 0.0f;                                            \
    int off_cur##N;                                                           \
    {                                                                         \
        const float klo = (float)((SEGV) * (NXV_ / NSEG));                    \
        const float khi = (float)(((SEGV) + 1) * (NXV_ / NSEG));              \
        const float aA = alpha_mul(klo, spx, sx, inv_dx);                     \
        const float aB = alpha_mul(khi, spx, sx, inv_dx);                     \
        start##N = fmaxf(amin, fminf(aA, aB));                                \
        aend##N  = fminf(amax, fmaxf(aA, aB));                                \
        const bool live = start##N < aend##N;                                 \
        {                                                                     \
            float kf = (start##N * dx + sx) * inv_spx;                        \
            kx##N = (dx > 0.f) ? floorf(kf) + 1.f : ceilf(kf) - 1.f;          \
            axv##N = alpha_mul(kx##N, spx, sx, inv_dx);                       \
        }                                                                     \
        {                                                                     \
            float kf = (start##N * dy + sy) * inv_spy;                        \
            ky##N = (dy > 0.f) ? floorf(kf) + 1.f : ceilf(kf) - 1.f;          \
            ayv##N = alpha_mul(ky##N, spy, sy, inv_dy);                       \
        }                                                                     \
        {                                                                     \
            float kf = (start##N * dz + sz) * inv_spz;                        \
            kz##N = (dz > 0.f) ? floorf(kf) + 1.f : ceilf(kf) - 1.f;          \
            azv##N = alpha_mul(kz##N, spz, sz, inv_dz);                       \
        }                                                                     \
        {                                                                     \
            float an0 = fminf(axv##N, fminf(ayv##N, azv##N));                 \
            float midv = 0.5f * (start##N + an0);                             \
            int ix = (int)((sx + midv * dx) * inv_spx);   /* trunc = ref */   \
            int iy = (int)((sy + midv * dy) * inv_spy);                       \
            int iz = (int)((sz + midv * dz) * inv_spz);                       \
            ix = min(max(ix, 0), NXV_ - 1);                                   \
            iy = min(max(iy, 0), NYV_ - 1);                                   \
            iz = min(max(iz, 0), NZV_ - 1);                                   \
            off_cur##N = ((NXV_ - 1 - ix) * NYV_ + iy) * NZV_ + iz;           \
        }                                                                     \
        a_cur##N = start##N;                                                  \
        if (!live) aend##N = -3.0e38f;                                        \
    }

__global__ void __launch_bounds__(512, 6)   // cap ~84 VGPR; est. peak ~74, no spill
drr_tile(const float* __restrict__ vol,
         const float* __restrict__ spacing,
         const float* __restrict__ sdr,
         const float* __restrict__ rot,
         const float* __restrict__ trans,
         float* __restrict__ out) {
    // bijective XCD swizzle (m204): neighbors on one XCD share volume regions
    const int nwg = gridDim.x;               // B * TILES_PER_IMG
    const int q8 = nwg >> 3, r8 = nwg & 7;
    const int xcd = blockIdx.x & 7;
    const int sub = blockIdx.x >> 3;
    const int wg = (xcd < r8 ? xcd * (q8 + 1) : r8 * (q8 + 1) + (xcd - r8) * q8) + sub;

    const int t = threadIdx.x;
    const int pixLocal = t & 63;            // 0..63 : 4x16 patch per wave
    const int seg1 = t >> 6;                // 0..7 ; chain2 walks seg1+8

    const int b    = wg / TILES_PER_IMG;
    const int rem  = wg % TILES_PER_IMG;
    const int ty   = rem / TCOLS;
    const int tx   = rem % TCOLS;
    const int i = ty * TILE_R + (pixLocal >> 4);   // 4 rows
    const int j = tx * TILE_C + (pixLocal & 15);   // 16 cols (may exceed W_-1: padded)

    // --- rotation matrix R = Rz(theta) Ry(phi) Rx(gamma) --- (once per ray,
    // shared by both chains; round-0 computed this 16x/pixel, now 8x)
    const float theta = rot[b * 3 + 0], phi = rot[b * 3 + 1], gamma = rot[b * 3 + 2];
    const float ct = cosf(theta), st = sinf(theta);
    const float cp = cosf(phi),   sp = sinf(phi);
    const float cg = cosf(gamma), sg = sinf(gamma);
    const float r00 = ct * cp,                r10 = st * cp,                r20 = -sp;
    const float r01 = ct * sp * sg - st * cg, r11 = st * sp * sg + ct * cg, r21 = cp * sg;
    const float r02 = ct * sp * cg + st * sg, r12 = st * sp * cg - ct * sg, r22 = cp * cg;

    const float sd = sdr[b];
    const float tx_ = trans[b * 3 + 0], ty_ = trans[b * 3 + 1], tz_ = trans[b * 3 + 2];
    const float sx = sd * r00 + tx_, sy = sd * r10 + ty_, sz = sd * r20 + tz_;
    const float cxx = -sd * r00 + tx_, cyy = -sd * r10 + ty_, czz = -sd * r20 + tz_;

    const float tco = ((float)(i - H_ / 2) + 1.0f) * DELX_;
    const float sco = ((float)(j - W_ / 2) + 1.0f) * DELY_;
    const float gx = r01 * tco + r02 * sco + cxx;
    const float gy = r11 * tco + r12 * sco + cyy;
    const float gz = r21 * tco + r22 * sco + czz;

    const float dx = gx - sx + EPS_;
    const float dy = gy - sy + EPS_;
    const float dz = gz - sz + EPS_;

    const float spx = spacing[0], spy = spacing[1], spz = spacing[2];
    const float inv_spx = 1.0f / spx, inv_spy = 1.0f / spy, inv_spz = 1.0f / spz;
    const float inv_dx = 1.0f / dx, inv_dy = 1.0f / dy, inv_dz = 1.0f / dz;

    const float a0x = alpha_mul(0.f, spx, sx, inv_dx), a1x = alpha_mul((float)NXV_, spx, sx, inv_dx);
    const float a0y = alpha_mul(0.f, spy, sy, inv_dy), a1y = alpha_mul((float)NYV_, spy, sy, inv_dy);
    const float a0z = alpha_mul(0.f, spz, sz, inv_dz), a1z = alpha_mul((float)NZV_, spz, sz, inv_dz);

    const float amin = fmaxf(fmaxf(fminf(a0x, a1x), fminf(a0y, a1y)), fminf(a0z, a1z));
    const float amax = fminf(fminf(fmaxf(a0x, a1x), fmaxf(a0y, a1y)), fmaxf(a0z, a1z));

    const float norm = sqrtf(dx * dx + dy * dy + dz * dz);

    // direction-only constants, shared by both chains (bitwise = round-0's
    // per-seg values, which depended only on d signs)
    const float dkx = (dx > 0.f) ? 1.f : -1.f;
    const float dky = (dy > 0.f) ? 1.f : -1.f;
    const float dkz = (dz > 0.f) ? 1.f : -1.f;
    const int doffx = (dx > 0.f) ? -(NYV_ * NZV_) : (NYV_ * NZV_);  // flipped x
    const int doffy = (dy > 0.f) ? NZV_ : -NZV_;
    const int doffz = (dz > 0.f) ? 1 : -1;

    INIT_CH(1, seg1)
    INIT_CH(2, seg1 + 8)

    // group loop: march both chains interleaved (2 independent dep-chains =
    // 2x march ILP), burst 8 loads, one wait, consume. Arrays die within the
    // iteration — the only structure this compiler compiles without scratch.
    #pragma unroll 1
    for (int g = 0; g < MAXG; ++g) {
        int   off1[G4], off2[G4];
        float stp1[G4], stp2[G4], v1[G4], v2[G4];
        STEPC(1, 0) STEPC(2, 0)
        STEPC(1, 1) STEPC(2, 1)
        STEPC(1, 2) STEPC(2, 2)
        STEPC(1, 3) STEPC(2, 3)
        #pragma unroll
        for (int u = 0; u < G4; ++u) { v1[u] = vol[off1[u]]; v2[u] = vol[off2[u]]; }
        #pragma unroll
        for (int u = 0; u < G4; ++u) { acc1 += v1[u] * stp1[u]; }
        #pragma unroll
        for (int u = 0; u < G4; ++u) { acc2 += v2[u] * stp2[u]; }
        if (__all((a_cur1 > aend1) && (a_cur2 > aend2))) break;
    }

    // block covers ALL 16 segs -> fused reduce, exact round-0+combine
    // association: (sum segs0-7 in k-order) + (sum segs8-15 in k-order)
    __shared__ float red[NSEG * 64];        // 4 KB
    red[seg1 * 64 + pixLocal]       = acc1 * norm;
    red[(seg1 + 8) * 64 + pixLocal] = acc2 * norm;
    __syncthreads();
    if (t < 64) {
        const int ii = ty * TILE_R + (t >> 4);
        const int jj = tx * TILE_C + (t & 15);
        if (jj < W_) {                          // mask padded columns
            float sLo = 0.0f, sHi = 0.0f;
            #pragma unroll
            for (int k = 0; k < 8; ++k) sLo += red[k * 64 + t];
            #pragma unroll
            for (int k = 8; k < 16; ++k) sHi += red[k * 64 + t];
            out[b * (H_ * W_) + ii * W_ + jj] = sLo + sHi;
        }
    }
}

extern "C" void kernel_launch(void* const* d_in, const int* in_sizes, int n_in,
                              void* d_out, int out_size, void* d_ws, size_t ws_size,
                              hipStream_t stream) {
    const float* vol     = (const float*)d_in[0];
    const float* spacing = (const float*)d_in[1];
    const float* sdr     = (const float*)d_in[2];
    const float* rot     = (const float*)d_in[3];
    const float* trans   = (const float*)d_in[4];
    float* out = (float*)d_out;

    const int B = in_sizes[2];
    drr_tile<<<B * TILES_PER_IMG, 512, 0, stream>>>(vol, spacing, sdr, rot, trans, out);
}

// Round 7
// 119.872 us; speedup vs baseline: 1.3962x; 1.0210x over previous
//
#include <hip/hip_runtime.h>

#define H_ 200
#define W_ 200
#define DELX_ 1.5f
#define DELY_ 1.5f
#define NXV_ 256
#define NYV_ 256
#define NZV_ 256
#define EPS_ 1e-8f
#define NSEG 16           // x-slabs of 16 planes (round-0 partition, proven absmax 3.0)
#define SEGS_PER_BLK 8    // block = 64 px * 8 segs = 512 threads; 2 blocks/tile
#define TILE_R 4          // 4x16 detector patch = 64 px = one wave per seg
#define TILE_C 16
#define TROWS (H_ / TILE_R)              // 50
#define TCOLS ((W_ + TILE_C - 1) / TILE_C)  // 13 (padded: last col tile partial)
#define TILES_PER_IMG (TROWS * TCOLS)    // 650
#define G_ 8              // steps per group (gathers in flight per group)
#define MAXG 10           // 10 groups * 8 = 80 steps >= worst-case per 16-slab

// alpha for integer plane k — SAME source expression as round-0 so the
// compiler's contraction is bitwise-identical (proven absmax 3.0 x5 rounds).
__device__ __forceinline__ float alpha_mul(float k, float sp, float src, float inv_sdd) {
    return (k * sp - src) * inv_sdd;
}

__global__ void __launch_bounds__(512, 8)   // round-0's bound: <=64 VGPR, 32 waves/CU capacity
drr_partial(const float* __restrict__ vol,
            const float* __restrict__ spacing,
            const float* __restrict__ sdr,
            const float* __restrict__ rot,
            const float* __restrict__ trans,
            float* __restrict__ partials,
            int npix) {
    // bijective XCD swizzle (m204): same-XCD blocks are contiguous tiles of one
    // seg-half -> shared volume regions stay in that XCD's L2 (perf-only).
    const int nwg = gridDim.x;               // B * TILES_PER_IMG * 2
    const int q8 = nwg >> 3, r8 = nwg & 7;
    const int xcd = blockIdx.x & 7;
    const int sub = blockIdx.x >> 3;
    const int wg = (xcd < r8 ? xcd * (q8 + 1) : r8 * (q8 + 1) + (xcd - r8) * q8) + sub;

    const int ntiles = nwg >> 1;             // B * TILES_PER_IMG
    const int half    = (wg < ntiles) ? 0 : 1;
    const int tileBlk = wg - half * ntiles;

    const int t = threadIdx.x;
    const int pixLocal = t & 63;            // 0..63 : 4x16 patch per wave
    const int seg = (t >> 6) + (half << 3); // 0..15 ; wave = 64 px x 1 slab

    const int b    = tileBlk / TILES_PER_IMG;
    const int rem  = tileBlk % TILES_PER_IMG;
    const int ty   = rem / TCOLS;
    const int tx   = rem % TCOLS;
    const int i = ty * TILE_R + (pixLocal >> 4);   // 4 rows
    const int j = tx * TILE_C + (pixLocal & 15);   // 16 cols (may exceed W_-1: padded)

    // --- rotation matrix R = Rz(theta) Ry(phi) Rx(gamma) ---
    const float theta = rot[b * 3 + 0], phi = rot[b * 3 + 1], gamma = rot[b * 3 + 2];
    const float ct = cosf(theta), st = sinf(theta);
    const float cp = cosf(phi),   sp = sinf(phi);
    const float cg = cosf(gamma), sg = sinf(gamma);
    const float r00 = ct * cp,                r10 = st * cp,                r20 = -sp;
    const float r01 = ct * sp * sg - st * cg, r11 = st * sp * sg + ct * cg, r21 = cp * sg;
    const float r02 = ct * sp * cg + st * sg, r12 = st * sp * cg - ct * sg, r22 = cp * cg;

    const float sd = sdr[b];
    const float tx_ = trans[b * 3 + 0], ty_ = trans[b * 3 + 1], tz_ = trans[b * 3 + 2];
    const float sx = sd * r00 + tx_, sy = sd * r10 + ty_, sz = sd * r20 + tz_;
    const float cxx = -sd * r00 + tx_, cyy = -sd * r10 + ty_, czz = -sd * r20 + tz_;

    const float tco = ((float)(i - H_ / 2) + 1.0f) * DELX_;
    const float sco = ((float)(j - W_ / 2) + 1.0f) * DELY_;
    const float gx = r01 * tco + r02 * sco + cxx;
    const float gy = r11 * tco + r12 * sco + cyy;
    const float gz = r21 * tco + r22 * sco + czz;

    const float dx = gx - sx + EPS_;
    const float dy = gy - sy + EPS_;
    const float dz = gz - sz + EPS_;

    const float spx = spacing[0], spy = spacing[1], spz = spacing[2];
    const float inv_spx = 1.0f / spx, inv_spy = 1.0f / spy, inv_spz = 1.0f / spz;
    const float inv_dx = 1.0f / dx, inv_dy = 1.0f / dy, inv_dz = 1.0f / dz;

    const float a0x = alpha_mul(0.f, spx, sx, inv_dx), a1x = alpha_mul((float)NXV_, spx, sx, inv_dx);
    const float a0y = alpha_mul(0.f, spy, sy, inv_dy), a1y = alpha_mul((float)NYV_, spy, sy, inv_dy);
    const float a0z = alpha_mul(0.f, spz, sz, inv_dz), a1z = alpha_mul((float)NZV_, spz, sz, inv_dz);

    const float amin = fmaxf(fmaxf(fminf(a0x, a1x), fminf(a0y, a1y)), fminf(a0z, a1z));
    const float amax = fminf(fminf(fmaxf(a0x, a1x), fmaxf(a0y, a1y)), fmaxf(a0z, a1z));

    const float norm = sqrtf(dx * dx + dy * dy + dz * dz);

    // segment bounds at x-plane crossings (exact members of the crossing set)
    const float klo = (float)(seg * (NXV_ / NSEG));
    const float khi = (float)((seg + 1) * (NXV_ / NSEG));
    const float aA = alpha_mul(klo, spx, sx, inv_dx);
    const float aB = alpha_mul(khi, spx, sx, inv_dx);
    const float start = fmaxf(amin, fminf(aA, aB));
    const float aend  = fminf(amax, fmaxf(aA, aB));

    float acc = 0.0f;
    if (start < aend) {
        float kx, ky, kz, axv, ayv, azv, dkx, dky, dkz;
        {
            float kf = (start * dx + sx) * inv_spx;
            if (dx > 0.f) { dkx = 1.f;  kx = floorf(kf) + 1.f; }
            else          { dkx = -1.f; kx = ceilf(kf) - 1.f; }
            axv = alpha_mul(kx, spx, sx, inv_dx);
        }
        {
            float kf = (start * dy + sy) * inv_spy;
            if (dy > 0.f) { dky = 1.f;  ky = floorf(kf) + 1.f; }
            else          { dky = -1.f; ky = ceilf(kf) - 1.f; }
            ayv = alpha_mul(ky, spy, sy, inv_dy);
        }
        {
            float kf = (start * dz + sz) * inv_spz;
            if (dz > 0.f) { dkz = 1.f;  kz = floorf(kf) + 1.f; }
            else          { dkz = -1.f; kz = ceilf(kf) - 1.f; }
            azv = alpha_mul(kz, spz, sz, inv_dz);
        }

        // initial cell from first-interval midpoint (clamped once), then
        // incremental single-offset walk (exit-face crossing suppressed)
        int off_cur;
        {
            float an0 = fminf(axv, fminf(ayv, azv));
            float midv = 0.5f * (start + an0);
            int ix = (int)((sx + midv * dx) * inv_spx);   // trunc, matches ref
            int iy = (int)((sy + midv * dy) * inv_spy);
            int iz = (int)((sz + midv * dz) * inv_spz);
            ix = min(max(ix, 0), NXV_ - 1);
            iy = min(max(iy, 0), NYV_ - 1);
            iz = min(max(iz, 0), NZV_ - 1);
            off_cur = ((NXV_ - 1 - ix) * NYV_ + iy) * NZV_ + iz;  // flip axis 0
        }
        const int doffx = (dkx > 0.f) ? -(NYV_ * NZV_) : (NYV_ * NZV_);  // flipped x
        const int doffy = (dky > 0.f) ? NZV_ : -NZV_;
        const int doffz = (dkz > 0.f) ? 1 : -1;

        float a_cur = start;
        // group loop: identical to round-0 EXCEPT the gather for step u issues
        // AT step u (same address round-0 stored into off[u]) so it ages under
        // the remaining march steps; consume waits per-load, in order. All
        // arrays die within the iteration (the proven no-spill pattern).
        #pragma unroll 1
        for (int g = 0; g < MAXG; ++g) {
            float stp[G_];
            float v[G_];
            #pragma unroll
            for (int u = 0; u < G_; ++u) {
                float an = fminf(axv, fminf(ayv, azv));
                bool ok = (an <= aend);
                stp[u] = ok ? (an - a_cur) : 0.0f;
                v[u] = vol[off_cur];          // issue gather now; ages under march
                a_cur = an;
                bool upd = (an < aend);
                bool cx = (axv == an), cy = (ayv == an), cz = (azv == an);
                kx = cx ? kx + dkx : kx;
                ky = cy ? ky + dky : ky;
                kz = cz ? kz + dkz : kz;
                off_cur += ((cx && upd) ? doffx : 0)
                         + ((cy && upd) ? doffy : 0)
                         + ((cz && upd) ? doffz : 0);
                axv = alpha_mul(kx, spx, sx, inv_dx);  // bitwise-stable recompute
                ayv = alpha_mul(ky, spy, sy, inv_dy);
                azv = alpha_mul(kz, spz, sz, inv_dz);
            }
            #pragma unroll
            for (int u = 0; u < G_; ++u) acc += v[u] * stp[u];
            if (__all(a_cur > aend)) break;   // proven-equivalent wave-uniform exit
        }
    }
    float result = acc * norm;

    // block-level reduce over the 8 segs of this half, fixed k-order summation
    __shared__ float red[SEGS_PER_BLK * 64];
    red[t] = result;
    __syncthreads();
    if (t < 64) {
        const int ii = ty * TILE_R + (t >> 4);
        const int jj = tx * TILE_C + (t & 15);
        if (jj < W_) {                          // mask padded columns
            const int opix = b * (H_ * W_) + ii * W_ + jj;
            float s = 0.0f;
            #pragma unroll
            for (int k = 0; k < SEGS_PER_BLK; k++) s += red[t + k * 64];
            partials[(size_t)half * npix + opix] = s;
        }
    }
}

__global__ void __launch_bounds__(256)
drr_combine(const float* __restrict__ partials, float* __restrict__ out, int npix) {
    int pix = blockIdx.x * blockDim.x + threadIdx.x;
    if (pix >= npix) return;
    out[pix] = partials[pix] + partials[(size_t)npix + pix];  // segs 0-7 then 8-15
}

extern "C" void kernel_launch(void* const* d_in, const int* in_sizes, int n_in,
                              void* d_out, int out_size, void* d_ws, size_t ws_size,
                              hipStream_t stream) {
    const float* vol     = (const float*)d_in[0];
    const float* spacing = (const float*)d_in[1];
    const float* sdr     = (const float*)d_in[2];
    const float* rot     = (const float*)d_in[3];
    const float* trans   = (const float*)d_in[4];
    float* out = (float*)d_out;

    const int B = in_sizes[2];
    const int npix = B * H_ * W_;
    float* partials = (float*)d_ws;     // 2 * npix floats

    const int nblocks = B * TILES_PER_IMG * 2;
    drr_partial<<<nblocks, 64 * SEGS_PER_BLK, 0, stream>>>(vol, spacing, sdr, rot, trans, partials, npix);
    drr_combine<<<(npix + 255) / 256, 256, 0, stream>>>(partials, out, npix);
}

// Round 8
// 119.244 us; speedup vs baseline: 1.4036x; 1.0053x over previous
//
#include <hip/hip_runtime.h>

#define H_ 200
#define W_ 200
#define DELX_ 1.5f
#define DELY_ 1.5f
#define NXV_ 256
#define NYV_ 256
#define NZV_ 256
#define EPS_ 1e-8f
#define NSEG 16           // x-slabs of 16 planes each (round-0 partition, proven absmax 3.0)
#define SEGS_PER_BLK 8    // block = 64 px * 8 segs = 512 threads; 2 blocks/tile
#define TILE_R 4          // 4x16 detector patch = 64 px = one wave per seg
#define TILE_C 16
#define TROWS (H_ / TILE_R)              // 50
#define TCOLS ((W_ + TILE_C - 1) / TILE_C)  // 13 (padded: last col tile partial)
#define TILES_PER_IMG (TROWS * TCOLS)    // 650
#define G_ 16             // steps per group: 2x round-0 -> half as many exposed
                          // load-tails per wave; avg slab needs ~24-32 steps = 2 groups
#define MAXG 5            // 5 * 16 = 80 steps capacity, identical to round-0

// alpha for integer plane k — SAME source expression as round-0 so the
// compiler's contraction is bitwise-identical (proven absmax 3.0 x6 rounds).
__device__ __forceinline__ float alpha_mul(float k, float sp, float src, float inv_sdd) {
    return (k * sp - src) * inv_sdd;
}

__global__ void __launch_bounds__(512, 6)   // cap 84 VGPR: fits v[16]+stp[16]+state (~75), no spill
drr_partial(const float* __restrict__ vol,
            const float* __restrict__ spacing,
            const float* __restrict__ sdr,
            const float* __restrict__ rot,
            const float* __restrict__ trans,
            float* __restrict__ partials,
            int npix) {
    const int t = threadIdx.x;
    const int pixLocal = t & 63;            // 0..63 : 4x16 patch per wave
    const int half = blockIdx.x & 1;        // seg-half of this block
    const int seg = (t >> 6) + (half << 3); // 0..15 ; wave = 64 px x 1 slab
    const int tileBlk = blockIdx.x >> 1;

    const int b    = tileBlk / TILES_PER_IMG;
    const int rem  = tileBlk % TILES_PER_IMG;
    const int ty   = rem / TCOLS;
    const int tx   = rem % TCOLS;
    const int i = ty * TILE_R + (pixLocal >> 4);   // 4 rows
    const int j = tx * TILE_C + (pixLocal & 15);   // 16 cols (may exceed W_-1: padded)

    // --- rotation matrix R = Rz(theta) Ry(phi) Rx(gamma) ---
    const float theta = rot[b * 3 + 0], phi = rot[b * 3 + 1], gamma = rot[b * 3 + 2];
    const float ct = cosf(theta), st = sinf(theta);
    const float cp = cosf(phi),   sp = sinf(phi);
    const float cg = cosf(gamma), sg = sinf(gamma);
    const float r00 = ct * cp,                r10 = st * cp,                r20 = -sp;
    const float r01 = ct * sp * sg - st * cg, r11 = st * sp * sg + ct * cg, r21 = cp * sg;
    const float r02 = ct * sp * cg + st * sg, r12 = st * sp * cg - ct * sg, r22 = cp * cg;

    const float sd = sdr[b];
    const float tx_ = trans[b * 3 + 0], ty_ = trans[b * 3 + 1], tz_ = trans[b * 3 + 2];
    const float sx = sd * r00 + tx_, sy = sd * r10 + ty_, sz = sd * r20 + tz_;
    const float cxx = -sd * r00 + tx_, cyy = -sd * r10 + ty_, czz = -sd * r20 + tz_;

    const float tco = ((float)(i - H_ / 2) + 1.0f) * DELX_;
    const float sco = ((float)(j - W_ / 2) + 1.0f) * DELY_;
    const float gx = r01 * tco + r02 * sco + cxx;
    const float gy = r11 * tco + r12 * sco + cyy;
    const float gz = r21 * tco + r22 * sco + czz;

    const float dx = gx - sx + EPS_;
    const float dy = gy - sy + EPS_;
    const float dz = gz - sz + EPS_;

    const float spx = spacing[0], spy = spacing[1], spz = spacing[2];
    const float inv_spx = 1.0f / spx, inv_spy = 1.0f / spy, inv_spz = 1.0f / spz;
    const float inv_dx = 1.0f / dx, inv_dy = 1.0f / dy, inv_dz = 1.0f / dz;

    const float a0x = alpha_mul(0.f, spx, sx, inv_dx), a1x = alpha_mul((float)NXV_, spx, sx, inv_dx);
    const float a0y = alpha_mul(0.f, spy, sy, inv_dy), a1y = alpha_mul((float)NYV_, spy, sy, inv_dy);
    const float a0z = alpha_mul(0.f, spz, sz, inv_dz), a1z = alpha_mul((float)NZV_, spz, sz, inv_dz);

    const float amin = fmaxf(fmaxf(fminf(a0x, a1x), fminf(a0y, a1y)), fminf(a0z, a1z));
    const float amax = fminf(fminf(fmaxf(a0x, a1x), fmaxf(a0y, a1y)), fmaxf(a0z, a1z));

    const float norm = sqrtf(dx * dx + dy * dy + dz * dz);

    // segment bounds at x-plane crossings (exact members of the crossing set;
    // identical formula across segments -> bitwise-consistent partition)
    const float klo = (float)(seg * (NXV_ / NSEG));
    const float khi = (float)((seg + 1) * (NXV_ / NSEG));
    const float aA = alpha_mul(klo, spx, sx, inv_dx);
    const float aB = alpha_mul(khi, spx, sx, inv_dx);
    const float lo = fminf(aA, aB), hi = fmaxf(aA, aB);

    const float start = fmaxf(amin, lo);
    const float aend  = fminf(amax, hi);

    float acc = 0.0f;
    if (start < aend) {
        float kx, ky, kz, axv, ayv, azv, dkx, dky, dkz;
        {
            float kf = (start * dx + sx) * inv_spx;
            if (dx > 0.f) { dkx = 1.f;  kx = floorf(kf) + 1.f; }
            else          { dkx = -1.f; kx = ceilf(kf) - 1.f; }
            axv = alpha_mul(kx, spx, sx, inv_dx);
        }
        {
            float kf = (start * dy + sy) * inv_spy;
            if (dy > 0.f) { dky = 1.f;  ky = floorf(kf) + 1.f; }
            else          { dky = -1.f; ky = ceilf(kf) - 1.f; }
            ayv = alpha_mul(ky, spy, sy, inv_dy);
        }
        {
            float kf = (start * dz + sz) * inv_spz;
            if (dz > 0.f) { dkz = 1.f;  kz = floorf(kf) + 1.f; }
            else          { dkz = -1.f; kz = ceilf(kf) - 1.f; }
            azv = alpha_mul(kz, spz, sz, inv_dz);
        }

        // initial cell from first-interval midpoint (clamped once), then
        // incremental single-offset walk (exit-face crossing suppressed)
        int off_cur;
        {
            float an0 = fminf(axv, fminf(ayv, azv));
            float midv = 0.5f * (start + an0);
            int ix = (int)((sx + midv * dx) * inv_spx);   // trunc, matches ref
            int iy = (int)((sy + midv * dy) * inv_spy);
            int iz = (int)((sz + midv * dz) * inv_spz);
            ix = min(max(ix, 0), NXV_ - 1);
            iy = min(max(iy, 0), NYV_ - 1);
            iz = min(max(iz, 0), NZV_ - 1);
            off_cur = ((NXV_ - 1 - ix) * NYV_ + iy) * NZV_ + iz;  // flip axis 0
        }
        const int doffx = (dkx > 0.f) ? -(NYV_ * NZV_) : (NYV_ * NZV_);  // flipped x
        const int doffy = (dky > 0.f) ? NZV_ : -NZV_;
        const int doffz = (dkz > 0.f) ? 1 : -1;

        float a_cur = start;
        // groups of G_=16 steps: identical recurrence and per-step numerics to
        // round-0 (groups of 8) — only the exit-check cadence changes. Early-
        // finished lanes produce stp=0 -> exact +0.0 adds, so acc is bitwise
        // round-0's. Loads hoist to their address-ready points (compiler does
        // this); the exposed end-of-group load tail now occurs 2-3x per wave
        // instead of 4-5x. All arrays die within the iteration (no-spill).
        #pragma unroll 1
        for (int g = 0; g < MAXG; ++g) {
            float stp[G_];
            int   off[G_];
            #pragma unroll
            for (int u = 0; u < G_; ++u) {
                float an = fminf(axv, fminf(ayv, azv));
                bool ok = (an <= aend);
                stp[u] = ok ? (an - a_cur) : 0.0f;
                off[u] = off_cur;                 // cell of interval [a_cur, an]
                a_cur = an;
                bool upd = (an < aend);           // suppress past/at segment end
                bool cx = (axv == an), cy = (ayv == an), cz = (azv == an);
                kx = cx ? kx + dkx : kx;
                ky = cy ? ky + dky : ky;
                kz = cz ? kz + dkz : kz;
                off_cur += ((cx && upd) ? doffx : 0)
                         + ((cy && upd) ? doffy : 0)
                         + ((cz && upd) ? doffz : 0);
                axv = alpha_mul(kx, spx, sx, inv_dx);  // bitwise-stable recompute
                ayv = alpha_mul(ky, spy, sy, inv_dy);
                azv = alpha_mul(kz, spz, sz, inv_dz);
            }
            float v[G_];
            #pragma unroll
            for (int u = 0; u < G_; ++u) v[u] = vol[off[u]];
            #pragma unroll
            for (int u = 0; u < G_; ++u) acc += v[u] * stp[u];
            if (__all(a_cur > aend)) break;       // wave-uniform exit
        }
    }
    float result = acc * norm;

    // block-level reduce over the 8 segs of this half, fixed k-order summation
    __shared__ float red[SEGS_PER_BLK * 64];
    red[t] = result;
    __syncthreads();
    if (t < 64) {
        const int ii = ty * TILE_R + (t >> 4);
        const int jj = tx * TILE_C + (t & 15);
        if (jj < W_) {                          // mask padded columns
            const int opix = b * (H_ * W_) + ii * W_ + jj;
            float s = 0.0f;
            #pragma unroll
            for (int k = 0; k < SEGS_PER_BLK; k++) s += red[t + k * 64];
            partials[(size_t)half * npix + opix] = s;
        }
    }
}

__global__ void __launch_bounds__(256)
drr_combine(const float* __restrict__ partials, float* __restrict__ out, int npix) {
    int pix = blockIdx.x * blockDim.x + threadIdx.x;
    if (pix >= npix) return;
    out[pix] = partials[pix] + partials[(size_t)npix + pix];  // segs 0-7 then 8-15
}

extern "C" void kernel_launch(void* const* d_in, const int* in_sizes, int n_in,
                              void* d_out, int out_size, void* d_ws, size_t ws_size,
                              hipStream_t stream) {
    const float* vol     = (const float*)d_in[0];
    const float* spacing = (const float*)d_in[1];
    const float* sdr     = (const float*)d_in[2];
    const float* rot     = (const float*)d_in[3];
    const float* trans   = (const float*)d_in[4];
    float* out = (float*)d_out;

    const int B = in_sizes[2];
    const int npix = B * H_ * W_;
    float* partials = (float*)d_ws;     // 2 * npix floats

    const int nblocks = B * TILES_PER_IMG * 2;
    drr_partial<<<nblocks, 64 * SEGS_PER_BLK, 0, stream>>>(vol, spacing, sdr, rot, trans, partials, npix);
    drr_combine<<<(npix + 255) / 256, 256, 0, stream>>>(partials, out, npix);
}